// Round 1
// baseline (545.318 us; speedup 1.0000x reference)
//
#include <hip/hip_runtime.h>
#include <cstdint>
#include <cstddef>

// Fused: h = x @ W^T + b ; per-row instance-norm over 2048 feats ; out = (normed+y)*y
// B=32768, IN=128, OUT=2048, fp32 in/out.
// R3: y is streamed into LDS via global_load_lds DURING the MFMA phase (one 1-KB
// staging instruction per MFMA tile -> vmcnt in-order retirement paces the GEMM at
// the HBM y-arrival rate, i.e. the roofline). Epilogue is a single flat pass:
// normalize in C-layout, ds_read y from LDS (2-way bank aliasing = free with the
// 2052-float pitch), fuse, scalar store. This removes R2's 4 serialized
// chunk fences that capped the y stream at ~4 loads in flight per wave.

#define IN_DIM  128
#define OUT_DIM 2048
#define ROWS    16      // rows per block
#define YPITCH  2052    // floats; 8208 B row pitch: 16B-aligned, 2-way-free banks
#define EPS     1e-5f

typedef short  short8  __attribute__((ext_vector_type(8)));   // 8 bf16 bits
typedef float  floatx4 __attribute__((ext_vector_type(4)));

__device__ __forceinline__ unsigned short f2bf(float f) {
    union { float f; unsigned int u; } v; v.f = f;
    unsigned int u = v.u;
    u += 0x7fffu + ((u >> 16) & 1u);   // round-to-nearest-even
    return (unsigned short)(u >> 16);
}

// Kernel 1: convert linear_w fp32 -> bf16 (bit pattern in ushort) into ws.
__global__ void convert_w_kernel(const float* __restrict__ w,
                                 unsigned short* __restrict__ wbf, int n) {
    int i = (blockIdx.x * blockDim.x + threadIdx.x) * 4;
    if (i < n) {
        float4 v = *(const float4*)(w + i);
        ushort4 o;
        o.x = f2bf(v.x); o.y = f2bf(v.y); o.z = f2bf(v.z); o.w = f2bf(v.w);
        *(ushort4*)(wbf + i) = o;
    }
}

// Main fused kernel: 512 threads = 8 waves. Wave w owns cols [w*256, w*256+256).
// Block owns rows [blockIdx.x*16, +16). 132.5 KB LDS -> 1 block/CU (intentional:
// the y stream is issued ~13K cycles ahead of use, so occupancy isn't needed to
// hide its latency).
__global__ __launch_bounds__(512)
void fused_linear_norm_kernel(const float* __restrict__ x,
                              const float* __restrict__ y,
                              const unsigned short* __restrict__ wbf,
                              const float* __restrict__ lb,
                              const float* __restrict__ nw,
                              const float* __restrict__ nb,
                              float* __restrict__ out) {
    const int tid  = threadIdx.x;
    const int wave = tid >> 6;        // 0..7
    const int lane = tid & 63;
    const int l15  = lane & 15;
    const int quad = lane >> 4;       // 0..3
    const int row0 = blockIdx.x * ROWS;

    __shared__ float ylds[ROWS * YPITCH];          // 131,328 B
    __shared__ float red1[8][ROWS];
    __shared__ float red2[8][ROWS];
    __shared__ float smean[ROWS], sinv[ROWS];

    // ---- A fragments FIRST (before any y staging: must not queue behind the
    // y-batch in vmcnt order). x rows, fp32 -> bf16 on load. 4 K-steps of 32. ----
    // A layout: lane holds A[m=lane&15][k = quad*8 + j], j=0..7
    short8 afrag[4];
    {
        const float* xr = x + (size_t)(row0 + l15) * IN_DIM + quad * 8;
        #pragma unroll
        for (int s = 0; s < 4; ++s) {
            float4 p0 = *(const float4*)(xr + s * 32);
            float4 p1 = *(const float4*)(xr + s * 32 + 4);
            short8 a;
            a[0] = (short)f2bf(p0.x); a[1] = (short)f2bf(p0.y);
            a[2] = (short)f2bf(p0.z); a[3] = (short)f2bf(p0.w);
            a[4] = (short)f2bf(p1.x); a[5] = (short)f2bf(p1.y);
            a[6] = (short)f2bf(p1.z); a[7] = (short)f2bf(p1.w);
            afrag[s] = a;
        }
    }

    // ---- MFMA main: 16 tiles of 16x16, K=128 in 4 steps; one y-staging
    // global_load_lds per tile (wave w stages rows {2w, 2w+1}, 8 segs each). ----
    // B layout: lane holds B[k=quad*8+j][n=lane&15]; B[k][n] = W[n][k], W row-major
    floatx4 acc[16];
    const int c0 = wave * 256;
    const float* ybase = y + (size_t)row0 * OUT_DIM;
    #pragma unroll
    for (int t = 0; t < 16; ++t) {
        acc[t] = (floatx4){0.f, 0.f, 0.f, 0.f};
        const unsigned short* wp = wbf + (size_t)(c0 + t * 16 + l15) * IN_DIM + quad * 8;
        #pragma unroll
        for (int s = 0; s < 4; ++s) {
            short8 b = *(const short8*)(wp + s * 32);
            acc[t] = __builtin_amdgcn_mfma_f32_16x16x32_bf16(afrag[s], b, acc[t], 0, 0, 0);
        }
        // stage one 1-KB segment of y: global 1 KB contiguous -> LDS linear
        // (wave-uniform base + lane*16, per m104/m108; pad lives at row END only)
        {
            const int r   = 2 * wave + (t >> 3);   // 0..15 (wave-uniform)
            const int seg = t & 7;                 // 0..7, 256-float segments
            const float* gp = ybase + (size_t)r * OUT_DIM + seg * 256 + lane * 4;
            float* lp = &ylds[r * YPITCH + seg * 256];
            __builtin_amdgcn_global_load_lds(
                (const __attribute__((address_space(1))) void*)gp,
                (__attribute__((address_space(3))) void*)lp, 16, 0, 0);
        }
    }

    // ---- bias add + per-row partial sums ----
    // C/D layout: col = c0 + t*16 + (lane&15); row = quad*4 + r
    float s1[4] = {0.f, 0.f, 0.f, 0.f};
    float s2[4] = {0.f, 0.f, 0.f, 0.f};
    #pragma unroll
    for (int t = 0; t < 16; ++t) {
        int col = c0 + t * 16 + l15;
        float bv = lb[col];
        #pragma unroll
        for (int r = 0; r < 4; ++r) {
            float h = acc[t][r] + bv;
            acc[t][r] = h;
            s1[r] += h;
            s2[r] += h * h;
        }
    }

    // butterfly over the 16-lane quad (quads own disjoint rows)
    #pragma unroll
    for (int off = 1; off < 16; off <<= 1) {
        #pragma unroll
        for (int r = 0; r < 4; ++r) {
            s1[r] += __shfl_xor(s1[r], off);
            s2[r] += __shfl_xor(s2[r], off);
        }
    }

    if (l15 == 0) {
        #pragma unroll
        for (int r = 0; r < 4; ++r) {
            red1[wave][quad * 4 + r] = s1[r];
            red2[wave][quad * 4 + r] = s2[r];
        }
    }
    __syncthreads();
    if (tid < ROWS) {
        float t1 = 0.f, t2 = 0.f;
        #pragma unroll
        for (int w = 0; w < 8; ++w) { t1 += red1[w][tid]; t2 += red2[w][tid]; }
        float mean = t1 * (1.0f / OUT_DIM);
        float var  = t2 * (1.0f / OUT_DIM) - mean * mean;
        smean[tid] = mean;
        sinv[tid]  = rsqrtf(var + EPS);
    }
    // Drain y staging (all waves) then barrier: after this, ylds is fully
    // populated and visible block-wide. (__syncthreads drains vmcnt before
    // s_barrier anyway; explicit drain is belt-and-braces.)
    __asm__ volatile("s_waitcnt vmcnt(0)" ::: "memory");
    __syncthreads();

    float mean[4], inv[4];
    #pragma unroll
    for (int r = 0; r < 4; ++r) {
        mean[r] = smean[quad * 4 + r];
        inv[r]  = sinv[quad * 4 + r];
    }

    // ---- epilogue: single flat pass in C-layout. y from LDS (ds_read_b32,
    // 2-way bank aliasing = free at pitch 2052), scalar dword stores (4 rows x
    // 64 B coalesced segments per instruction; stores don't stall the wave). ----
    #pragma unroll
    for (int t = 0; t < 16; ++t) {
        const int col = c0 + t * 16 + l15;
        const float gw = nw[col];
        const float gb = nb[col];
        #pragma unroll
        for (int r = 0; r < 4; ++r) {
            const int rl = quad * 4 + r;
            const float normed = (acc[t][r] - mean[r]) * inv[r] * gw + gb;
            const float yv = ylds[rl * YPITCH + col];
            const float o  = (normed + yv) * yv;
            out[(size_t)(row0 + rl) * OUT_DIM + col] = o;
        }
    }
}

extern "C" void kernel_launch(void* const* d_in, const int* in_sizes, int n_in,
                              void* d_out, int out_size, void* d_ws, size_t ws_size,
                              hipStream_t stream) {
    const float* x  = (const float*)d_in[0];
    const float* y  = (const float*)d_in[1];
    const float* lw = (const float*)d_in[2];
    const float* lb = (const float*)d_in[3];
    const float* nw = (const float*)d_in[4];
    const float* nb = (const float*)d_in[5];
    float* out = (float*)d_out;
    unsigned short* wbf = (unsigned short*)d_ws;   // 2048*128*2B = 512 KB

    const int wn = OUT_DIM * IN_DIM;               // 262144
    convert_w_kernel<<<wn / 4 / 256, 256, 0, stream>>>(lw, wbf, wn);

    const int nblocks = 32768 / ROWS;              // 2048
    fused_linear_norm_kernel<<<nblocks, 512, 0, stream>>>(x, y, wbf, lb, nw, nb, out);
}